// Round 15
// baseline (30.924 us; speedup 1.0000x reference)
//
#include <hip/hip_runtime.h>
#include <hip/hip_fp16.h>

// HalutMatmul forward on MI355X.
// Per row n: h[c][p] = sum_d I[n, c*9+d] * A[c][d][p]   (c=0..15, p=0..3)
//            code_c  = 4-level tree descent: bit_l = (h[c][l] > T[c*15 + node_l])
//            out[n][m] = sum_c L[m][c][code_c]
//
// Round-15: THE clean occupancy experiment. Empirical cap model from R4/R12/
// R13 spills: launch_bounds(256,w) caps VGPR at ~256/w. (256,>=3) caps below
// the ~110-reg demand -> spills poisoned every occupancy test. (256,2) caps
// at 128 >= demand -> no spill, AND occupancy is set by resources anyway:
// LDS 34KB -> 4 blocks/CU, VGPR<=128 -> 16 waves/CU. Kernel body = R13
// verbatim (absmax 0.0039 proven):
//  - no I staging: hash lanes read global directly (L1 absorbs 36B stride).
//  - codes packed in-wave via shfl_xor -> 2KB sCodes.
//  - f32 hash + 1e-3 borderline guard + exact-f64 fallback (codes bit-exact).
//  - bank-exact f16 b64 gather (2-way free), swizzled transpose epilogue.

#define NROWS (1024 * 128)

typedef __attribute__((ext_vector_type(2))) float f32x2;

__global__ __launch_bounds__(256, 2) void halut_fwd(
    const float* __restrict__ I,
    const float* __restrict__ A,
    const float* __restrict__ T,
    const float* __restrict__ L,
    float* __restrict__ out)
{
    __shared__ uint32_t sLut[8192];   // 32KB f16 LUT; reused as epilogue staging
    __shared__ uint32_t sCodes[512];  // 128 rows x 4 u32 (16 codes, 8b each)

    const int tid  = threadIdx.x;
    const int w    = tid >> 6;
    const int lane = tid & 63;
    const int cB   = lane & 15;       // hash: codebook
    const int g    = lane >> 4;       // hash: row-in-pass

    // ---- per-lane constants: codebook cB's A and T in VGPRs ----
    f32x2 a01[9], a23[9];
    {
        const float4* ap4 = (const float4*)(A + cB * 36);   // 144B-aligned
        #pragma unroll
        for (int i = 0; i < 9; ++i) {
            const float4 v = ap4[i];
            a01[i] = (f32x2){v.x, v.y};
            a23[i] = (f32x2){v.z, v.w};
        }
    }
    float Tf[15];
    #pragma unroll
    for (int j = 0; j < 15; ++j) Tf[j] = T[cB * 15 + j];

    // ---- stage f16 LUT: phys uint2 idx = i*512 + col*2 + mh (col = tid) ----
    {
        uint4* dst = (uint4*)sLut;                 // uint4 idx = i*256 + tid
        #pragma unroll
        for (int i = 0; i < 8; ++i) {
            uint32_t wv[4];
            #pragma unroll
            for (int mh2 = 0; mh2 < 2; ++mh2) {
                const int mb = mh2 * 32 + 4 * i;
                const float fa = L[(mb + 0) * 256 + tid];
                const float fb = L[(mb + 1) * 256 + tid];
                const float fc = L[(mb + 2) * 256 + tid];
                const float fd = L[(mb + 3) * 256 + tid];
                wv[mh2*2+0] = ((uint32_t)__half_as_ushort(__float2half_rn(fb)) << 16)
                            |  (uint32_t)__half_as_ushort(__float2half_rn(fa));
                wv[mh2*2+1] = ((uint32_t)__half_as_ushort(__float2half_rn(fd)) << 16)
                            |  (uint32_t)__half_as_ushort(__float2half_rn(fc));
            }
            dst[i * 256 + tid] = make_uint4(wv[0], wv[1], wv[2], wv[3]);
        }
    }
    __syncthreads();

    // ---- hash: 8 passes x 4 rows, direct global reads, 1-deep prefetch ----
    const int brow0 = blockIdx.x * 128;
    const float* gb = I + (size_t)(brow0 + w * 32 + g) * 144 + cB * 9;

    float xb[2][9];
    #pragma unroll
    for (int d = 0; d < 9; ++d) xb[0][d] = gb[d];

    #pragma unroll
    for (int ps = 0; ps < 8; ++ps) {                 // fully unrolled: static idx
        const float* xc = xb[ps & 1];
        if (ps < 7) {
            float* xn = xb[(ps + 1) & 1];
            #pragma unroll
            for (int d = 0; d < 9; ++d) xn[d] = gb[(ps + 1) * 576 + d];
        }
        f32x2 h01 = (f32x2){0.f, 0.f}, h23 = (f32x2){0.f, 0.f};
        #pragma unroll
        for (int d = 0; d < 9; ++d) {
            const f32x2 xx = (f32x2){xc[d], xc[d]};
            h01 = __builtin_elementwise_fma(xx, a01[d], h01);
            h23 = __builtin_elementwise_fma(xx, a23[d], h23);
        }
        const float hh[4] = {h01.x, h01.y, h23.x, h23.y};
        uint32_t mk = 0, bl = 0;
        #pragma unroll
        for (int j = 0; j < 15; ++j) {
            const int lv = (j == 0) ? 0 : (j < 3) ? 1 : (j < 7) ? 2 : 3;
            const float b = hh[lv] - Tf[j];
            mk |= (b > 0.f) ? (1u << j) : 0u;
            bl |= (fabsf(b) < 1e-3f) ? 1u : 0u;
        }
        if (bl) {   // rare borderline: exact f64, FMA order of rounds 1-10
            double h0 = 0.0, h1 = 0.0, h2 = 0.0, h3 = 0.0;
            #pragma unroll
            for (int d = 0; d < 9; ++d) {
                const double x = (double)xc[d];
                h0 = fma(x, (double)a01[d].x, h0);
                h1 = fma(x, (double)a01[d].y, h1);
                h2 = fma(x, (double)a23[d].x, h2);
                h3 = fma(x, (double)a23[d].y, h3);
            }
            const double hd[4] = {h0, h1, h2, h3};
            mk = 0;
            #pragma unroll
            for (int j = 0; j < 15; ++j) {
                const int lv = (j == 0) ? 0 : (j < 3) ? 1 : (j < 7) ? 2 : 3;
                mk |= (hd[lv] > (double)Tf[j]) ? (1u << j) : 0u;
            }
        }
        int p =       (int)(mk & 1u);
        p = 2 * p + (int)((mk >> (1 + p)) & 1u);
        p = 2 * p + (int)((mk >> (3 + p)) & 1u);
        p = 2 * p + (int)((mk >> (7 + p)) & 1u);

        // pack 4 codes/u32 across the cB-quad; one lane per quad writes
        uint32_t v = (uint32_t)p << (8 * (cB & 3));
        v |= __shfl_xor(v, 1);
        v |= __shfl_xor(v, 2);
        if ((lane & 3) == 0)
            sCodes[(w * 32 + ps * 4 + g) * 4 + (cB >> 2)] = v;
    }

    // ---- gather: 2 thr/row, bank-exact 2-way-free b64 reads ----
    const int lr = tid >> 1;          // 0..127
    const int mh = tid & 1;           // m-half
    const uint4 cw = ((const uint4*)sCodes)[lr];   // same-wave rows: no barrier

    __half2 acc2[16];
    #pragma unroll
    for (int k = 0; k < 16; ++k) acc2[k] = __floats2half2_rn(0.f, 0.f);

    const uint2* lut2 = (const uint2*)sLut;
    #pragma unroll 4
    for (int c = 0; c < 16; ++c) {
        const uint32_t cdw = (c < 4) ? cw.x : (c < 8) ? cw.y : (c < 12) ? cw.z : cw.w;
        const int p    = (int)((cdw >> ((c & 3) * 8)) & 15u);
        const int col2 = (c * 16 + p) * 2 + mh;
        #pragma unroll
        for (int i = 0; i < 8; ++i) {             // m-quad = mh*8+i
            const uint2 uv = lut2[i * 512 + col2];
            acc2[2*i]   = __hadd2(acc2[2*i],   *(const __half2*)&uv.x);
            acc2[2*i+1] = __hadd2(acc2[2*i+1], *(const __half2*)&uv.y);
        }
    }

    // ---- epilogue: swizzled LDS transpose (proven), 128 rows, one pass ----
    __syncthreads();                  // all gathers done; LUT region dead
    float* sO = (float*)sLut;         // [128 rows][64 m], 16B-chunk swizzle
    #pragma unroll
    for (int k2 = 0; k2 < 8; ++k2) {
        const int ch = mh * 8 + k2;   // global float4 chunk = m/4
        const float4 v = make_float4(__low2float (acc2[2*k2]),
                                     __high2float(acc2[2*k2]),
                                     __low2float (acc2[2*k2+1]),
                                     __high2float(acc2[2*k2+1]));
        *(float4*)&sO[(lr << 6) + ((ch ^ (lr & 15)) << 2)] = v;
    }
    __syncthreads();

    float4* op = (float4*)(out + (size_t)blockIdx.x * (128 * 64));
    #pragma unroll
    for (int j = 0; j < 8; ++j) {     // 2048 float4 = 32 KiB, contiguous
        const int F  = tid + (j << 8);
        const int r2 = F >> 4;
        const int m2 = F & 15;
        op[F] = *(const float4*)&sO[(r2 << 6) + ((m2 ^ (r2 & 15)) << 2)];
    }
}

extern "C" void kernel_launch(void* const* d_in, const int* in_sizes, int n_in,
                              void* d_out, int out_size, void* d_ws, size_t ws_size,
                              hipStream_t stream) {
    const float* I = (const float*)d_in[0];
    const float* A = (const float*)d_in[1];
    const float* T = (const float*)d_in[2];
    const float* L = (const float*)d_in[3];
    float* outp = (float*)d_out;

    const int nblocks = NROWS / 128;   // 1024 blocks x 256 threads
    halut_fwd<<<nblocks, 256, 0, stream>>>(I, A, T, L, outp);
}